// Round 2
// 402.263 us; speedup vs baseline: 1.0345x; 1.0345x over previous
//
#include <hip/hip_runtime.h>
#include <math.h>

// LinformerAttention on MI355X — Round 8: 256x256 8-phase counted-vmcnt GEMM
// (T1+T2+T3+T4+T5) with STATIC 128 KiB LDS (no dynamic-LDS attribute, no host
// API calls in kernel_launch — R7 container-failure suspects removed).
// B=8 T=2048 C=1024 H=16 D=64 Kproj=128. ws ~180 MB.

constexpr int B_ = 8, T_ = 2048, C_ = 1024, H_ = 16, D_ = 64, KP = 128;
constexpr int M_ = B_ * T_;            // 16384
constexpr int C3 = 3 * C_;             // 3072
constexpr int K_ = C_;                 // GEMM K = 1024
constexpr int NT = K_ / 64;            // 16 K-tiles of 64
constexpr int TCH = 4;                 // proj t-chunks of 512

typedef __attribute__((ext_vector_type(8))) short bf16x8;   // 8 bf16 = 4 VGPR
typedef __attribute__((ext_vector_type(4))) float f32x4;

__device__ __forceinline__ unsigned short f2bf(float f) {
  unsigned u = __builtin_bit_cast(unsigned, f);
  u += 0x7FFFu + ((u >> 16) & 1u);     // round-to-nearest-even
  return (unsigned short)(u >> 16);
}
__device__ __forceinline__ float bf2f(unsigned short h) {
  unsigned u = ((unsigned)h) << 16;
  return __builtin_bit_cast(float, u);
}

#define GLOAD_LDS16(gptr, lptr)                                                \
  __builtin_amdgcn_global_load_lds(                                            \
      (const __attribute__((address_space(1))) void*)(gptr),                   \
      (__attribute__((address_space(3))) void*)(lptr), 16, 0, 0)

// ---------------------------------------------------------------------------
// fp32 -> bf16 (hi) cast, row-major. n4 = n/4.
// ---------------------------------------------------------------------------
__global__ __launch_bounds__(256) void cast_bf16(
    const float* __restrict__ in, unsigned short* __restrict__ hi, int n4)
{
  int i = blockIdx.x * 256 + threadIdx.x;
  if (i >= n4) return;
  const float4 v = reinterpret_cast<const float4*>(in)[i];
  ushort4 h;
  h.x = f2bf(v.x); h.y = f2bf(v.y); h.z = f2bf(v.z); h.w = f2bf(v.w);
  reinterpret_cast<ushort4*>(hi)[i] = h;
}

// ---------------------------------------------------------------------------
// Transpose + bf16: W [rows][cols] fp32 -> T [cols][rows] bf16.
// ---------------------------------------------------------------------------
__global__ __launch_bounds__(256) void cast_tr(
    const float* __restrict__ W, unsigned short* __restrict__ Tb,
    int rows, int cols)
{
  __shared__ float tile[32][33];
  const int c0 = blockIdx.x * 32, r0 = blockIdx.y * 32;
  const int tx = threadIdx.x & 31, ty = threadIdx.x >> 5;   // ty 0..7
  #pragma unroll
  for (int i = 0; i < 4; ++i)
    tile[ty + i * 8][tx] = W[(size_t)(r0 + ty + i * 8) * cols + c0 + tx];
  __syncthreads();
  #pragma unroll
  for (int i = 0; i < 4; ++i) {
    const int cr = ty + i * 8;
    Tb[(size_t)(c0 + cr) * rows + r0 + tx] = f2bf(tile[tx][cr]);
  }
}

// ---------------------------------------------------------------------------
// 256x256 8-phase GEMM: C(16384 x ldc) = A(MxK) @ BT^T + bias, K=1024.
// BT is [N][K] bf16. 512 threads = 8 waves (2M x 4N); per-wave 128x64 out.
// LDS 128 KiB STATIC: 2 buffers x (A 32KB + B 32KB). Per K-tile: 4 phases,
// one C-quadrant (16 MFMA) each; 1 half-tile (2 x global_load_lds16) staged
// per phase; boundary wait vmcnt(6) (= newest 6 loads = tile t+2's A0,B0,B1
// still in flight; everything tile t+1 needs forced complete), never 0
// mid-loop. LDS rows region-permuted (A: qm*128+wr*64+rr; B: qn*128+wc*32+rr)
// so each staged half is contiguous; XOR swizzle (byte bits 9->5, 10->4)
// applied on the pre-swizzled global source AND the ds_read address.
// ---------------------------------------------------------------------------
template <bool BFOUT>
__global__ __launch_bounds__(512, 2) void gemm256(
    const unsigned short* __restrict__ A, const unsigned short* __restrict__ BT,
    const float* __restrict__ bias, float* __restrict__ Cf,
    unsigned short* __restrict__ Cb, int ldc)
{
  __shared__ __attribute__((aligned(16))) char lds[131072];

  const int tid  = threadIdx.x;
  const int lane = tid & 63;
  const int w    = tid >> 6;           // 0..7
  const int wr   = w >> 2;             // 0..1 (M)
  const int wc   = w & 3;              // 0..3 (N)
  const int col  = lane & 15;
  const int quad = lane >> 4;

  // T1: bijective XCD-chunked block swizzle (gridDim.x % 8 == 0 here).
  const int ntx = ldc >> 8;
  int wg = blockIdx.x;
  wg = (wg & 7) * (gridDim.x >> 3) + (wg >> 3);
  const int bx = wg % ntx, by = wg / ntx;
  const int m0 = by << 8, n0 = bx << 8;

  // --- staging geometry (per thread, 2 loads per half-tile) ---
  // phys dest (region-rel) = w*2048 + l*1024 + lane*16 ; logical = phys ^
  // (bit9<<5) ^ (bit10<<4); bit9 = lane>>5, bit10 = l.
  int mOff[2], nOff[2], csh[2];
  #pragma unroll
  for (int l = 0; l < 2; ++l) {
    const int rl = w * 16 + l * 8 + (lane >> 3);        // logical row 0..127
    mOff[l] = (rl >> 6) * 128 + (rl & 63);              // + h*64 -> global m
    nOff[l] = (rl >> 5) * 64 + (rl & 31);               // + h*32 -> global n
    csh[l]  = ((lane & 7) * 8) ^ (((lane >> 5) & 1) << 4) ^ (l << 3); // shorts
  }

#define STAGE_A(H, KT0, BUFSEL)                                                \
  { const int kb_ = (KT0) * 64;                                                \
    _Pragma("unroll")                                                          \
    for (int l = 0; l < 2; ++l)                                                \
      GLOAD_LDS16(A + (size_t)(m0 + mOff[l] + (H) * 64) * K_ + kb_ + csh[l],   \
                  lds + (BUFSEL) * 65536 + (H) * 16384 + w * 2048 + l * 1024); }

#define STAGE_B(H, KT0, BUFSEL)                                                \
  { const int kb_ = (KT0) * 64;                                                \
    _Pragma("unroll")                                                          \
    for (int l = 0; l < 2; ++l)                                                \
      GLOAD_LDS16(BT + (size_t)(n0 + nOff[l] + (H) * 32) * K_ + kb_ + csh[l],  \
                  lds + (BUFSEL) * 65536 + 32768 + (H) * 16384 + w * 2048 +    \
                      l * 1024); }

  // --- ds_read fragment addressing (bytes, swizzled) ---
  const int qsw = (quad * 16) ^ ((col & 4) << 3) ^ ((col & 8) << 1);
  const int aB0 = (wr * 64 + col) * 128;                 // A region qm=0
  const int aB1 = (128 + wr * 64 + col) * 128;           // A region qm=1
  const int bB0 = 32768 + (wc * 32 + col) * 128;         // B region qn=0
  const int bB1 = 32768 + (128 + wc * 32 + col) * 128;   // B region qn=1

  f32x4 acc[8][4];
  #pragma unroll
  for (int a = 0; a < 8; ++a)
    #pragma unroll
    for (int c = 0; c < 4; ++c)
      acc[a][c] = (f32x4){0.f, 0.f, 0.f, 0.f};

  bf16x8 av[4][2], b0v[2][2], b1v[2][2];

#define MFMA_Q(QM, QN, BV)                                                     \
  __builtin_amdgcn_s_setprio(1);                                               \
  _Pragma("unroll")                                                            \
  for (int j = 0; j < 2; ++j)                                                  \
    _Pragma("unroll")                                                          \
    for (int ks = 0; ks < 2; ++ks)                                             \
      _Pragma("unroll")                                                        \
      for (int i = 0; i < 4; ++i)                                              \
        acc[(QM) * 4 + i][(QN) * 2 + j] =                                      \
            __builtin_amdgcn_mfma_f32_16x16x32_bf16(                           \
                av[i][ks], BV[j][ks], acc[(QM) * 4 + i][(QN) * 2 + j], 0, 0, 0);\
  __builtin_amdgcn_s_setprio(0);

  // --- prologue: tile0 fully + tile1 {A0,B0,B1}; vmcnt(4) then vmcnt(6) ---
  STAGE_A(0, 0, 0);
  STAGE_B(0, 0, 0);
  STAGE_B(1, 0, 0);
  STAGE_A(1, 0, 0);
  asm volatile("s_waitcnt vmcnt(4)" ::: "memory");
  STAGE_A(0, 1, 1);
  STAGE_B(0, 1, 1);
  STAGE_B(1, 1, 1);
  asm volatile("s_waitcnt vmcnt(6)" ::: "memory");
  __builtin_amdgcn_s_barrier();

#define TILE(KT, CUR)                                                          \
  {                                                                            \
    const char* cb = lds + (CUR) * 65536;                                      \
    /* phase 1: quadrant (0,0); 12 ds_read; stage A1(t+1) */                   \
    _Pragma("unroll")                                                          \
    for (int i = 0; i < 4; ++i)                                                \
      _Pragma("unroll")                                                        \
      for (int ks = 0; ks < 2; ++ks)                                           \
        av[i][ks] = *reinterpret_cast<const bf16x8*>(                          \
            cb + aB0 + i * 2048 + ks * 64 + qsw);                              \
    _Pragma("unroll")                                                          \
    for (int j = 0; j < 2; ++j)                                                \
      _Pragma("unroll")                                                        \
      for (int ks = 0; ks < 2; ++ks)                                           \
        b0v[j][ks] = *reinterpret_cast<const bf16x8*>(                         \
            cb + bB0 + j * 2048 + ks * 64 + qsw);                              \
    if ((KT) + 1 < NT) { STAGE_A(1, (KT) + 1, (CUR) ^ 1); }                    \
    asm volatile("s_waitcnt lgkmcnt(8)" ::: "memory");                         \
    __builtin_amdgcn_s_barrier();                                              \
    asm volatile("s_waitcnt lgkmcnt(0)" ::: "memory");                         \
    __builtin_amdgcn_sched_barrier(0);                                         \
    MFMA_Q(0, 0, b0v);                                                         \
    __builtin_amdgcn_s_barrier();                                              \
    /* phase 2: quadrant (0,1); 4 ds_read; stage A0(t+2) */                    \
    _Pragma("unroll")                                                          \
    for (int j = 0; j < 2; ++j)                                                \
      _Pragma("unroll")                                                        \
      for (int ks = 0; ks < 2; ++ks)                                           \
        b1v[j][ks] = *reinterpret_cast<const bf16x8*>(                         \
            cb + bB1 + j * 2048 + ks * 64 + qsw);                              \
    if ((KT) + 2 < NT) { STAGE_A(0, (KT) + 2, (CUR)); }                        \
    __builtin_amdgcn_s_barrier();                                              \
    asm volatile("s_waitcnt lgkmcnt(0)" ::: "memory");                         \
    __builtin_amdgcn_sched_barrier(0);                                         \
    MFMA_Q(0, 1, b1v);                                                         \
    __builtin_amdgcn_s_barrier();                                              \
    /* phase 3: quadrant (1,1); 8 ds_read; stage B0(t+2) */                    \
    _Pragma("unroll")                                                          \
    for (int i = 0; i < 4; ++i)                                                \
      _Pragma("unroll")                                                        \
      for (int ks = 0; ks < 2; ++ks)                                           \
        av[i][ks] = *reinterpret_cast<const bf16x8*>(                          \
            cb + aB1 + i * 2048 + ks * 64 + qsw);                              \
    if ((KT) + 2 < NT) { STAGE_B(0, (KT) + 2, (CUR)); }                        \
    __builtin_amdgcn_s_barrier();                                              \
    asm volatile("s_waitcnt lgkmcnt(0)" ::: "memory");                         \
    __builtin_amdgcn_sched_barrier(0);                                         \
    MFMA_Q(1, 1, b1v);                                                         \
    __builtin_amdgcn_s_barrier();                                              \
    /* phase 4: quadrant (1,0); 0 ds_read; stage B1(t+2); boundary vmcnt */    \
    if ((KT) + 2 < NT) { STAGE_B(1, (KT) + 2, (CUR)); }                        \
    __builtin_amdgcn_s_barrier();                                              \
    __builtin_amdgcn_sched_barrier(0);                                         \
    MFMA_Q(1, 0, b0v);                                                         \
    if ((KT) < NT - 2) {                                                       \
      asm volatile("s_waitcnt vmcnt(6)" ::: "memory");                         \
    } else if ((KT) == NT - 2) {                                               \
      asm volatile("s_waitcnt vmcnt(0)" ::: "memory");                         \
    }                                                                          \
    __builtin_amdgcn_s_barrier();                                              \
  }

  for (int kt = 0; kt < NT; kt += 2) {
    TILE(kt, 0);
    TILE(kt + 1, 1);
  }
#undef TILE
#undef MFMA_Q
#undef STAGE_A
#undef STAGE_B

  // --- epilogue: C/D layout col=lane&15, row=quad*4+reg (session-verified) --
  #pragma unroll
  for (int a = 0; a < 8; ++a) {
    const int r = m0 + wr * 128 + (a >> 2) * 64 + (a & 3) * 16 + quad * 4;
    #pragma unroll
    for (int c = 0; c < 4; ++c) {
      const int cc = n0 + wc * 64 + (c >> 1) * 32 + (c & 1) * 16 + col;
      const float bv = bias[cc];
      #pragma unroll
      for (int rg = 0; rg < 4; ++rg) {
        const float v = acc[a][c][rg] + bv;
        const size_t o = (size_t)(r + rg) * ldc + cc;
        if constexpr (BFOUT) Cb[o] = f2bf(v);
        else Cf[o] = v;
      }
    }
  }
}

// ---------------------------------------------------------------------------
// MFMA proj (1-product): part[(bh*TCH+tc)][kk=128][d=64] fp32 =
//   sum_{t in 512-chunk} E[h][kk][t] * k[b*T+t][h*64+d]
// ---------------------------------------------------------------------------
__global__ __launch_bounds__(256) void proj_mfma(
    const unsigned short* __restrict__ Eh, const unsigned short* __restrict__ kb,
    int ldk, float* __restrict__ part)
{
  __shared__ unsigned short sE[KP * 72];           // 18.0 KB
  __shared__ unsigned short sK[D_ * 72];           //  9.0 KB

  const int bh = blockIdx.x;
  const int tc = blockIdx.y;
  const int b = bh >> 4, h = bh & 15;
  const int tid = threadIdx.x;
  const int lane = tid & 63;
  const int w = tid >> 6;
  const int col = lane & 15;
  const int quad = lane >> 4;
  const int tq = tid >> 4;            // 0..15 -> t-base tq*4
  const int dq = tid & 15;            // 0..15 -> d-base dq*4

  f32x4 acc[2][4];
  #pragma unroll
  for (int i = 0; i < 2; ++i)
    #pragma unroll
    for (int j = 0; j < 4; ++j) acc[i][j] = (f32x4){0.f, 0.f, 0.f, 0.f};

  for (int s = 0; s < 8; ++s) {
    const int t0 = tc * 512 + s * 64;
    #pragma unroll
    for (int l = 0; l < 4; ++l) {
      const int idx = l * 256 + tid;
      const int kk = idx >> 3, seg = idx & 7;
      *reinterpret_cast<uint4*>(sE + kk * 72 + seg * 8) =
          *reinterpret_cast<const uint4*>(
              Eh + (size_t)(h * KP + kk) * T_ + t0 + seg * 8);
    }
    {
      const size_t gbase = (size_t)(b * T_ + t0 + tq * 4) * ldk + h * D_ + dq * 4;
      ushort4 r[4];
      #pragma unroll
      for (int rr = 0; rr < 4; ++rr)
        r[rr] = *reinterpret_cast<const ushort4*>(kb + gbase + (size_t)rr * ldk);
      #pragma unroll
      for (int c = 0; c < 4; ++c) {
        ushort4 t;
        t.x = (&r[0].x)[c]; t.y = (&r[1].x)[c];
        t.z = (&r[2].x)[c]; t.w = (&r[3].x)[c];
        *reinterpret_cast<ushort4*>(sK + (dq * 4 + c) * 72 + tq * 4) = t;
      }
    }
    __syncthreads();

    bf16x8 av[2][2];
    #pragma unroll
    for (int i = 0; i < 2; ++i)
      #pragma unroll
      for (int ks = 0; ks < 2; ++ks)
        av[i][ks] = *reinterpret_cast<const bf16x8*>(
            sE + ((w * 2 + i) * 16 + col) * 72 + ks * 32 + quad * 8);
    #pragma unroll
    for (int j = 0; j < 4; ++j)
      #pragma unroll
      for (int ks = 0; ks < 2; ++ks) {
        const bf16x8 bv = *reinterpret_cast<const bf16x8*>(
            sK + (j * 16 + col) * 72 + ks * 32 + quad * 8);
        #pragma unroll
        for (int i = 0; i < 2; ++i)
          acc[i][j] = __builtin_amdgcn_mfma_f32_16x16x32_bf16(av[i][ks], bv, acc[i][j], 0, 0, 0);
      }
    __syncthreads();
  }

  float* op = part + ((size_t)bh * TCH + tc) * (KP * D_);
  #pragma unroll
  for (int i = 0; i < 2; ++i) {
    const int kkb = w * 32 + i * 16 + quad * 4;
    #pragma unroll
    for (int j = 0; j < 4; ++j) {
      const int d = j * 16 + col;
      #pragma unroll
      for (int rg = 0; rg < 4; ++rg)
        op[(kkb + rg) * D_ + d] = acc[i][j][rg];
    }
  }
}

// ---------------------------------------------------------------------------
// reduce_k: kprojh[bh][kk][d] (bf16) = sum_c part[bh][c][kk][d]
// ---------------------------------------------------------------------------
__global__ __launch_bounds__(256) void reduce_k(
    const float* __restrict__ part, unsigned short* __restrict__ kprojh)
{
  const int idx = blockIdx.x * 256 + threadIdx.x;   // over 128*8192
  const int bh = idx >> 13;
  const int i = idx & 8191;
  float s = 0.f;
  #pragma unroll
  for (int c = 0; c < TCH; ++c)
    s += part[((size_t)bh * TCH + c) * 8192 + i];
  kprojh[idx] = f2bf(s);
}

// ---------------------------------------------------------------------------
// reduce_v: vpT [bh][d][kk] bf16 = transpose(sum_c part[bh][c][kk][d])
// ---------------------------------------------------------------------------
__global__ __launch_bounds__(256) void reduce_v(
    const float* __restrict__ part, unsigned short* __restrict__ vpTh)
{
  __shared__ float sums[KP * 66];     // [kk][d] pitch 66
  const int bh = blockIdx.x;
  const int tid = threadIdx.x;
  #pragma unroll
  for (int j = 0; j < 32; ++j) {
    const int i = j * 256 + tid;      // kk = i>>6, d = i&63
    float s = 0.f;
    #pragma unroll
    for (int c = 0; c < TCH; ++c)
      s += part[((size_t)bh * TCH + c) * 8192 + i];
    sums[(i >> 6) * 66 + (i & 63)] = s;
  }
  __syncthreads();
  #pragma unroll
  for (int j = 0; j < 32; ++j) {
    const int i = j * 256 + tid;      // d = i>>7, kk = i&127
    vpTh[(size_t)bh * 8192 + i] = f2bf(sums[(i & 127) * 66 + (i >> 7)]);
  }
}

// ---------------------------------------------------------------------------
// MFMA attention (1-product): q bf16 from qkv[.., 0..C) (ld C3),
// kproj bf16 [kk][d], vpT bf16 [d][kk]; y bf16 out [M][C].
// ---------------------------------------------------------------------------
__global__ __launch_bounds__(256) void attn_mfma(
    const unsigned short* __restrict__ qkv, const unsigned short* __restrict__ kprojh,
    const unsigned short* __restrict__ vpTh, unsigned short* __restrict__ yh)
{
  // LDS union (35072 B): A: Qh@0(9216) Kp@9216(18432) end 27648
  //                      B: Vh@0(17408) Ps@17408(17408) atts@34816(256)
  __shared__ __attribute__((aligned(16))) char lds[35072];
  unsigned short* Qh = (unsigned short*)(lds);
  unsigned short* Kp = (unsigned short*)(lds + 9216);
  unsigned short* Vh = (unsigned short*)(lds);
  unsigned short* Ps = (unsigned short*)(lds + 17408);
  float* atts = (float*)(lds + 34816);

  const int tid  = threadIdx.x;
  const int lane = tid & 63;
  const int w    = tid >> 6;
  const int col  = lane & 15;
  const int quad = lane >> 4;
  const int bh = blockIdx.x >> 5;
  const int tch = blockIdx.x & 31;
  const int b = bh >> 4, h = bh & 15;
  const int t0 = tch * 64;

  { // stage Q (pitch 72) and Kp (pitch 72)
    const unsigned short* qg = qkv + (size_t)(b * T_ + t0) * C3 + h * D_;
    #pragma unroll
    for (int l = 0; l < 4; ++l) {
      const int idx = l * 256 + tid;
      const int t = idx >> 4, dc = (idx & 15) << 2;
      *reinterpret_cast<ushort4*>(Qh + t * 72 + dc) =
          *reinterpret_cast<const ushort4*>(qg + (size_t)t * C3 + dc);
    }
    const unsigned short* kg = kprojh + (size_t)bh * 8192;
    #pragma unroll
    for (int l = 0; l < 8; ++l) {
      const int idx = l * 256 + tid;
      const int kk = idx >> 4, dc = (idx & 15) << 2;
      *reinterpret_cast<ushort4*>(Kp + kk * 72 + dc) =
          *reinterpret_cast<const ushort4*>(kg + kk * 64 + dc);
    }
  }
  __syncthreads();

  // S^T = Kp(A) @ Q^T(B): m=kk (8 tiles), n=t (wave strip), k=d (2 steps)
  f32x4 s[8];
  #pragma unroll
  for (int i = 0; i < 8; ++i) s[i] = (f32x4){0.f, 0.f, 0.f, 0.f};
  bf16x8 bq[2];
  #pragma unroll
  for (int ks = 0; ks < 2; ++ks)
    bq[ks] = *reinterpret_cast<const bf16x8*>(
        Qh + (w * 16 + col) * 72 + ks * 32 + quad * 8);
  #pragma unroll
  for (int i = 0; i < 8; ++i)
    #pragma unroll
    for (int ks = 0; ks < 2; ++ks) {
      const bf16x8 a = *reinterpret_cast<const bf16x8*>(
          Kp + (i * 16 + col) * 72 + ks * 32 + quad * 8);
      s[i] = __builtin_amdgcn_mfma_f32_16x16x32_bf16(a, bq[ks], s[i], 0, 0, 0);
    }

  // softmax over kk (t = w*16+col)
  float mx = -3.0e38f;
  #pragma unroll
  for (int i = 0; i < 8; ++i)
    #pragma unroll
    for (int rg = 0; rg < 4; ++rg) {
      s[i][rg] *= 0.125f;
      mx = fmaxf(mx, s[i][rg]);
    }
  mx = fmaxf(mx, __shfl_xor(mx, 16));
  mx = fmaxf(mx, __shfl_xor(mx, 32));
  float sum = 0.f;
  #pragma unroll
  for (int i = 0; i < 8; ++i)
    #pragma unroll
    for (int rg = 0; rg < 4; ++rg) {
      const float e = __expf(s[i][rg] - mx);
      s[i][rg] = e;
      sum += e;
    }
  sum += __shfl_xor(sum, 16);
  sum += __shfl_xor(sum, 32);
  const float inv = 1.f / sum;
  __syncthreads();

  { // stage Vp (pitch 136)
    const unsigned short* vg = vpTh + (size_t)bh * 8192;
    #pragma unroll
    for (int l = 0; l < 8; ++l) {
      const int idx = l * 256 + tid;
      const int d = idx >> 5, kc = (idx & 31) << 2;
      *reinterpret_cast<ushort4*>(Vh + d * 136 + kc) =
          *reinterpret_cast<const ushort4*>(vg + d * 128 + kc);
    }
  }
  #pragma unroll
  for (int i = 0; i < 8; ++i) {
    ushort4 hp;
    hp.x = f2bf(s[i][0]); hp.y = f2bf(s[i][1]);
    hp.z = f2bf(s[i][2]); hp.w = f2bf(s[i][3]);
    *reinterpret_cast<ushort4*>(Ps + (w * 16 + col) * 136 + i * 16 + quad * 4) = hp;
  }
  if (quad == 0) atts[w * 16 + col] = inv;
  __syncthreads();

  // y = P(A) @ V(B): m=t (wave strip), n=d (4 tiles), k=kk (4 steps)
  f32x4 y[4];
  #pragma unroll
  for (int j = 0; j < 4; ++j) y[j] = (f32x4){0.f, 0.f, 0.f, 0.f};
  bf16x8 ap[4];
  #pragma unroll
  for (int ks = 0; ks < 4; ++ks)
    ap[ks] = *reinterpret_cast<const bf16x8*>(
        Ps + (w * 16 + col) * 136 + ks * 32 + quad * 8);
  #pragma unroll
  for (int j = 0; j < 4; ++j)
    #pragma unroll
    for (int ks = 0; ks < 4; ++ks) {
      const bf16x8 bv = *reinterpret_cast<const bf16x8*>(
          Vh + (j * 16 + col) * 136 + ks * 32 + quad * 8);
      y[j] = __builtin_amdgcn_mfma_f32_16x16x32_bf16(ap[ks], bv, y[j], 0, 0, 0);
    }

  const f32x4 inv4 = *reinterpret_cast<const f32x4*>(atts + w * 16 + quad * 4);
  #pragma unroll
  for (int j = 0; j < 4; ++j)
    #pragma unroll
    for (int rg = 0; rg < 4; ++rg) {
      const int t = t0 + w * 16 + quad * 4 + rg;
      const int d = j * 16 + col;
      yh[(size_t)(b * T_ + t) * C_ + h * D_ + d] = f2bf(y[j][rg] * inv4[rg]);
    }
}

// ---------------------------------------------------------------------------
extern "C" void kernel_launch(void* const* d_in, const int* in_sizes, int n_in,
                              void* d_out, int out_size, void* d_ws, size_t ws_size,
                              hipStream_t stream) {
  (void)in_sizes; (void)n_in; (void)out_size; (void)ws_size;
  const float* x      = (const float*)d_in[0];
  const float* W_attn = (const float*)d_in[1];
  const float* b_attn = (const float*)d_in[2];
  const float* W_proj = (const float*)d_in[3];
  const float* b_proj = (const float*)d_in[4];
  const float* E      = (const float*)d_in[5];
  const float* F      = (const float*)d_in[6];
  float* out = (float*)d_out;

  // ws regions, ~180.4 MB peak:
  unsigned short* xh   = (unsigned short*)d_ws;          // [M][C]  33.55 MB
  unsigned short* qkvh = xh + (size_t)M_ * C_;           // [M][3C] 100.66 MB
  unsigned short* WaT  = qkvh + (size_t)M_ * C3;         // [3072][1024] 6.29 MB
  unsigned short* WpT  = WaT + (size_t)C3 * C_;          // [1024][1024] 2.10 MB
  unsigned short* Eh   = WpT + (size_t)C_ * C_;          // 8.39 MB
  unsigned short* Fh   = Eh + (size_t)H_ * KP * T_;      // 8.39 MB
  float* part = (float*)(Fh + (size_t)H_ * KP * T_);     // 16.78 MB
  unsigned short* kprojh = (unsigned short*)(part + (size_t)B_ * H_ * TCH * KP * D_);
  unsigned short* vpTh   = kprojh + (size_t)B_ * H_ * KP * D_;   // 2.10 MB each
  unsigned short* yh = xh;                               // x dead after qkv GEMM

  // 0) casts / transposes
  cast_bf16<<<(M_ * C_ / 4 + 255) / 256, 256, 0, stream>>>(x, xh, M_ * C_ / 4);
  cast_bf16<<<(H_ * KP * T_ / 4 + 255) / 256, 256, 0, stream>>>(E, Eh, H_ * KP * T_ / 4);
  cast_bf16<<<(H_ * KP * T_ / 4 + 255) / 256, 256, 0, stream>>>(F, Fh, H_ * KP * T_ / 4);
  cast_tr<<<dim3(C3 / 32, C_ / 32), 256, 0, stream>>>(W_attn, WaT, C_, C3);
  cast_tr<<<dim3(C_ / 32, C_ / 32), 256, 0, stream>>>(W_proj, WpT, C_, C_);

  // 1) qkv = x @ W_attn + b_attn  (fused, N=3072, bf16 out) — 8-phase 256²
  gemm256<true><<<dim3((M_ / 256) * (C3 / 256)), 512, 0, stream>>>(
      xh, WaT, b_attn, nullptr, qkvh, C3);

  // 2) kproj = E @ k  (k = qkv cols [C,2C))
  proj_mfma<<<dim3(B_ * H_, TCH), 256, 0, stream>>>(Eh, qkvh + C_, C3, part);
  reduce_k<<<(B_ * H_ * KP * D_) / 256, 256, 0, stream>>>(part, kprojh);

  // 3) vpT = transpose(F @ v)  (v = qkv cols [2C,3C))
  proj_mfma<<<dim3(B_ * H_, TCH), 256, 0, stream>>>(Fh, qkvh + 2 * C_, C3, part);
  reduce_v<<<B_ * H_, 256, 0, stream>>>(part, vpTh);

  // 4) MFMA attention -> y bf16 (overwrites x region)
  attn_mfma<<<B_ * H_ * (T_ / 64), 256, 0, stream>>>(qkvh, kprojh, vpTh, yh);

  // 5) out = y @ W_proj + b_proj (fp32 out) — 8-phase 256²
  gemm256<false><<<dim3((M_ / 256) * (C_ / 256)), 512, 0, stream>>>(
      yh, WpT, b_proj, out, nullptr, C_);
}

// Round 3
// 384.486 us; speedup vs baseline: 1.0823x; 1.0462x over previous
//
#include <hip/hip_runtime.h>
#include <math.h>

// LinformerAttention on MI355X — Round 9: 8-phase 256x256 GEMM with
// FRAGMENT-LINEAR LDS layout: each MFMA fragment is a contiguous 1024B
// subtile in lane order, so every ds_read_b128 is base+lane*16 (zero bank
// conflicts by construction). Staging pre-permutes the per-lane GLOBAL
// source instead (global_load_lds dest stays linear). Schedule (phases,
// counted vmcnt(6), setprio, XCD swizzle) identical to R8.
// B=8 T=2048 C=1024 H=16 D=64 Kproj=128. ws ~180 MB.

constexpr int B_ = 8, T_ = 2048, C_ = 1024, H_ = 16, D_ = 64, KP = 128;
constexpr int M_ = B_ * T_;            // 16384
constexpr int C3 = 3 * C_;             // 3072
constexpr int K_ = C_;                 // GEMM K = 1024
constexpr int NT = K_ / 64;            // 16 K-tiles of 64
constexpr int TCH = 4;                 // proj t-chunks of 512

typedef __attribute__((ext_vector_type(8))) short bf16x8;   // 8 bf16 = 4 VGPR
typedef __attribute__((ext_vector_type(4))) float f32x4;

__device__ __forceinline__ unsigned short f2bf(float f) {
  unsigned u = __builtin_bit_cast(unsigned, f);
  u += 0x7FFFu + ((u >> 16) & 1u);     // round-to-nearest-even
  return (unsigned short)(u >> 16);
}
__device__ __forceinline__ float bf2f(unsigned short h) {
  unsigned u = ((unsigned)h) << 16;
  return __builtin_bit_cast(float, u);
}

#define GLOAD_LDS16(gptr, lptr)                                                \
  __builtin_amdgcn_global_load_lds(                                            \
      (const __attribute__((address_space(1))) void*)(gptr),                   \
      (__attribute__((address_space(3))) void*)(lptr), 16, 0, 0)

// ---------------------------------------------------------------------------
// fp32 -> bf16 (hi) cast, row-major. n4 = n/4.
// ---------------------------------------------------------------------------
__global__ __launch_bounds__(256) void cast_bf16(
    const float* __restrict__ in, unsigned short* __restrict__ hi, int n4)
{
  int i = blockIdx.x * 256 + threadIdx.x;
  if (i >= n4) return;
  const float4 v = reinterpret_cast<const float4*>(in)[i];
  ushort4 h;
  h.x = f2bf(v.x); h.y = f2bf(v.y); h.z = f2bf(v.z); h.w = f2bf(v.w);
  reinterpret_cast<ushort4*>(hi)[i] = h;
}

// ---------------------------------------------------------------------------
// Transpose + bf16: W [rows][cols] fp32 -> T [cols][rows] bf16.
// ---------------------------------------------------------------------------
__global__ __launch_bounds__(256) void cast_tr(
    const float* __restrict__ W, unsigned short* __restrict__ Tb,
    int rows, int cols)
{
  __shared__ float tile[32][33];
  const int c0 = blockIdx.x * 32, r0 = blockIdx.y * 32;
  const int tx = threadIdx.x & 31, ty = threadIdx.x >> 5;   // ty 0..7
  #pragma unroll
  for (int i = 0; i < 4; ++i)
    tile[ty + i * 8][tx] = W[(size_t)(r0 + ty + i * 8) * cols + c0 + tx];
  __syncthreads();
  #pragma unroll
  for (int i = 0; i < 4; ++i) {
    const int cr = ty + i * 8;
    Tb[(size_t)(c0 + cr) * rows + r0 + tx] = f2bf(tile[tx][cr]);
  }
}

// ---------------------------------------------------------------------------
// 256x256 8-phase GEMM: C(16384 x ldc) = A(MxK) @ BT^T + bias, K=1024.
// BT is [N][K] bf16. 512 threads = 8 waves (2M x 4N); per-wave 128x64 out.
// LDS 128 KiB static: 2 buf x (A 32KB + B 32KB), each 2 halves of 16KB.
//
// FRAGMENT-LINEAR layout. A half H (16KB) = 16 subtiles of 1024B:
//   byte = H*16384 + rg*2048 + ks*1024 + (q*16 + c)*16
//   logical: lds-row rl = rg*16+c (rg 0..7), k-elem = ks*32 + q*8 + e
//   global m row = (rl>>6)*128 + (rl&63) + H*64   (same mapping as R8)
// B half H likewise with n row = (rl>>5)*64 + (rl&31) + H*32.
// MFMA fragment reads are then base + lane*16: ZERO bank conflicts.
// Staging: dest = region + w*2048 + l*1024 + lane*16 (linear, rg=w, ks=l);
// source per lane (q=lane>>4, c=lane&15): row w*16+c, k = kt*64 + l*32 + q*8.
// Schedule: 4 phases/K-tile, 1 half staged per phase, boundary vmcnt(6).
// ---------------------------------------------------------------------------
template <bool BFOUT>
__global__ __launch_bounds__(512, 2) void gemm256(
    const unsigned short* __restrict__ A, const unsigned short* __restrict__ BT,
    const float* __restrict__ bias, float* __restrict__ Cf,
    unsigned short* __restrict__ Cb, int ldc)
{
  __shared__ __attribute__((aligned(16))) char lds[131072];

  const int tid  = threadIdx.x;
  const int lane = tid & 63;
  const int w    = tid >> 6;           // 0..7
  const int wr   = w >> 2;             // 0..1 (M)
  const int wc   = w & 3;              // 0..3 (N)
  const int col  = lane & 15;
  const int quad = lane >> 4;

  // T1: bijective XCD-chunked block swizzle (gridDim.x % 8 == 0 here).
  const int ntx = ldc >> 8;
  int wg = blockIdx.x;
  wg = (wg & 7) * (gridDim.x >> 3) + (wg >> 3);
  const int bx = wg % ntx, by = wg / ntx;
  const int m0 = by << 8, n0 = bx << 8;

  // --- staging geometry (per thread, 2 loads per half) ---
  const int kq   = quad * 8;                 // k sub-offset (bf16 elems)
  const int rowL = w * 16 + col;             // logical lds-row 0..127 (rg = w)
  const int mOff = (rowL >> 6) * 128 + (rowL & 63);
  const int nOff = (rowL >> 5) * 64 + (rowL & 31);
  const int dstO = w * 2048 + lane * 16;     // + l*1024

#define STAGE_A(H, KT0, BUFSEL)                                                \
  { const int kb_ = (KT0) * 64 + kq;                                           \
    _Pragma("unroll")                                                          \
    for (int l = 0; l < 2; ++l)                                                \
      GLOAD_LDS16(A + (size_t)(m0 + mOff + (H) * 64) * K_ + kb_ + l * 32,      \
                  lds + (BUFSEL) * 65536 + (H) * 16384 + dstO + l * 1024); }

#define STAGE_B(H, KT0, BUFSEL)                                                \
  { const int kb_ = (KT0) * 64 + kq;                                           \
    _Pragma("unroll")                                                          \
    for (int l = 0; l < 2; ++l)                                                \
      GLOAD_LDS16(BT + (size_t)(n0 + nOff + (H) * 32) * K_ + kb_ + l * 32,     \
                  lds + (BUFSEL) * 65536 + 32768 + (H) * 16384 + dstO +        \
                      l * 1024); }

  // --- ds_read fragment addressing: base + lane*16, fully linear ---
  const int laneB = lane * 16;
  const int aB0 = wr * 8192 + laneB;           // A half 0, rg = wr*4 + i
  const int aB1 = 16384 + aB0;                 // A half 1
  const int bB0 = 32768 + wc * 4096 + laneB;   // B half 0, rg = wc*2 + j
  const int bB1 = 16384 + bB0;                 // B half 1

  f32x4 acc[8][4];
  #pragma unroll
  for (int a = 0; a < 8; ++a)
    #pragma unroll
    for (int c = 0; c < 4; ++c)
      acc[a][c] = (f32x4){0.f, 0.f, 0.f, 0.f};

  bf16x8 av[4][2], b0v[2][2], b1v[2][2];

#define MFMA_Q(QM, QN, BV)                                                     \
  __builtin_amdgcn_s_setprio(1);                                               \
  _Pragma("unroll")                                                            \
  for (int j = 0; j < 2; ++j)                                                  \
    _Pragma("unroll")                                                          \
    for (int ks = 0; ks < 2; ++ks)                                             \
      _Pragma("unroll")                                                        \
      for (int i = 0; i < 4; ++i)                                              \
        acc[(QM) * 4 + i][(QN) * 2 + j] =                                      \
            __builtin_amdgcn_mfma_f32_16x16x32_bf16(                           \
                av[i][ks], BV[j][ks], acc[(QM) * 4 + i][(QN) * 2 + j], 0, 0, 0);\
  __builtin_amdgcn_s_setprio(0);

  // --- prologue: tile0 fully + tile1 {A0,B0,B1}; vmcnt(4) then vmcnt(6) ---
  STAGE_A(0, 0, 0);
  STAGE_B(0, 0, 0);
  STAGE_B(1, 0, 0);
  STAGE_A(1, 0, 0);
  asm volatile("s_waitcnt vmcnt(4)" ::: "memory");
  STAGE_A(0, 1, 1);
  STAGE_B(0, 1, 1);
  STAGE_B(1, 1, 1);
  asm volatile("s_waitcnt vmcnt(6)" ::: "memory");
  __builtin_amdgcn_s_barrier();

#define TILE(KT, CUR)                                                          \
  {                                                                            \
    const char* cb = lds + (CUR) * 65536;                                      \
    /* phase 1: quadrant (0,0); 12 ds_read; stage A1(t+1) */                   \
    _Pragma("unroll")                                                          \
    for (int i = 0; i < 4; ++i)                                                \
      _Pragma("unroll")                                                        \
      for (int ks = 0; ks < 2; ++ks)                                           \
        av[i][ks] = *reinterpret_cast<const bf16x8*>(                          \
            cb + aB0 + i * 2048 + ks * 1024);                                  \
    _Pragma("unroll")                                                          \
    for (int j = 0; j < 2; ++j)                                                \
      _Pragma("unroll")                                                        \
      for (int ks = 0; ks < 2; ++ks)                                           \
        b0v[j][ks] = *reinterpret_cast<const bf16x8*>(                         \
            cb + bB0 + j * 2048 + ks * 1024);                                  \
    if ((KT) + 1 < NT) { STAGE_A(1, (KT) + 1, (CUR) ^ 1); }                    \
    asm volatile("s_waitcnt lgkmcnt(8)" ::: "memory");                         \
    __builtin_amdgcn_s_barrier();                                              \
    asm volatile("s_waitcnt lgkmcnt(0)" ::: "memory");                         \
    __builtin_amdgcn_sched_barrier(0);                                         \
    MFMA_Q(0, 0, b0v);                                                         \
    __builtin_amdgcn_s_barrier();                                              \
    /* phase 2: quadrant (0,1); 4 ds_read; stage A0(t+2) */                    \
    _Pragma("unroll")                                                          \
    for (int j = 0; j < 2; ++j)                                                \
      _Pragma("unroll")                                                        \
      for (int ks = 0; ks < 2; ++ks)                                           \
        b1v[j][ks] = *reinterpret_cast<const bf16x8*>(                         \
            cb + bB1 + j * 2048 + ks * 1024);                                  \
    if ((KT) + 2 < NT) { STAGE_A(0, (KT) + 2, (CUR)); }                        \
    __builtin_amdgcn_s_barrier();                                              \
    asm volatile("s_waitcnt lgkmcnt(0)" ::: "memory");                         \
    __builtin_amdgcn_sched_barrier(0);                                         \
    MFMA_Q(0, 1, b1v);                                                         \
    __builtin_amdgcn_s_barrier();                                              \
    /* phase 3: quadrant (1,1); 8 ds_read; stage B0(t+2) */                    \
    _Pragma("unroll")                                                          \
    for (int i = 0; i < 4; ++i)                                                \
      _Pragma("unroll")                                                        \
      for (int ks = 0; ks < 2; ++ks)                                           \
        av[i][ks] = *reinterpret_cast<const bf16x8*>(                          \
            cb + aB1 + i * 2048 + ks * 1024);                                  \
    if ((KT) + 2 < NT) { STAGE_B(0, (KT) + 2, (CUR)); }                        \
    __builtin_amdgcn_s_barrier();                                              \
    asm volatile("s_waitcnt lgkmcnt(0)" ::: "memory");                         \
    __builtin_amdgcn_sched_barrier(0);                                         \
    MFMA_Q(1, 1, b1v);                                                         \
    __builtin_amdgcn_s_barrier();                                              \
    /* phase 4: quadrant (1,0); 0 ds_read; stage B1(t+2); boundary vmcnt */    \
    if ((KT) + 2 < NT) { STAGE_B(1, (KT) + 2, (CUR)); }                        \
    __builtin_amdgcn_s_barrier();                                              \
    __builtin_amdgcn_sched_barrier(0);                                         \
    MFMA_Q(1, 0, b0v);                                                         \
    if ((KT) < NT - 2) {                                                       \
      asm volatile("s_waitcnt vmcnt(6)" ::: "memory");                         \
    } else if ((KT) == NT - 2) {                                               \
      asm volatile("s_waitcnt vmcnt(0)" ::: "memory");                         \
    }                                                                          \
    __builtin_amdgcn_s_barrier();                                              \
  }

  for (int kt = 0; kt < NT; kt += 2) {
    TILE(kt, 0);
    TILE(kt + 1, 1);
  }
#undef TILE
#undef MFMA_Q
#undef STAGE_A
#undef STAGE_B

  // --- epilogue: C/D layout col=lane&15, row=quad*4+reg (session-verified) --
  #pragma unroll
  for (int a = 0; a < 8; ++a) {
    const int r = m0 + wr * 128 + (a >> 2) * 64 + (a & 3) * 16 + quad * 4;
    #pragma unroll
    for (int c = 0; c < 4; ++c) {
      const int cc = n0 + wc * 64 + (c >> 1) * 32 + (c & 1) * 16 + col;
      const float bv = bias[cc];
      #pragma unroll
      for (int rg = 0; rg < 4; ++rg) {
        const float v = acc[a][c][rg] + bv;
        const size_t o = (size_t)(r + rg) * ldc + cc;
        if constexpr (BFOUT) Cb[o] = f2bf(v);
        else Cf[o] = v;
      }
    }
  }
}

// ---------------------------------------------------------------------------
// MFMA proj (1-product): part[(bh*TCH+tc)][kk=128][d=64] fp32 =
//   sum_{t in 512-chunk} E[h][kk][t] * k[b*T+t][h*64+d]
// ---------------------------------------------------------------------------
__global__ __launch_bounds__(256) void proj_mfma(
    const unsigned short* __restrict__ Eh, const unsigned short* __restrict__ kb,
    int ldk, float* __restrict__ part)
{
  __shared__ unsigned short sE[KP * 72];           // 18.0 KB
  __shared__ unsigned short sK[D_ * 72];           //  9.0 KB

  const int bh = blockIdx.x;
  const int tc = blockIdx.y;
  const int b = bh >> 4, h = bh & 15;
  const int tid = threadIdx.x;
  const int lane = tid & 63;
  const int w = tid >> 6;
  const int col = lane & 15;
  const int quad = lane >> 4;
  const int tq = tid >> 4;            // 0..15 -> t-base tq*4
  const int dq = tid & 15;            // 0..15 -> d-base dq*4

  f32x4 acc[2][4];
  #pragma unroll
  for (int i = 0; i < 2; ++i)
    #pragma unroll
    for (int j = 0; j < 4; ++j) acc[i][j] = (f32x4){0.f, 0.f, 0.f, 0.f};

  for (int s = 0; s < 8; ++s) {
    const int t0 = tc * 512 + s * 64;
    #pragma unroll
    for (int l = 0; l < 4; ++l) {
      const int idx = l * 256 + tid;
      const int kk = idx >> 3, seg = idx & 7;
      *reinterpret_cast<uint4*>(sE + kk * 72 + seg * 8) =
          *reinterpret_cast<const uint4*>(
              Eh + (size_t)(h * KP + kk) * T_ + t0 + seg * 8);
    }
    {
      const size_t gbase = (size_t)(b * T_ + t0 + tq * 4) * ldk + h * D_ + dq * 4;
      ushort4 r[4];
      #pragma unroll
      for (int rr = 0; rr < 4; ++rr)
        r[rr] = *reinterpret_cast<const ushort4*>(kb + gbase + (size_t)rr * ldk);
      #pragma unroll
      for (int c = 0; c < 4; ++c) {
        ushort4 t;
        t.x = (&r[0].x)[c]; t.y = (&r[1].x)[c];
        t.z = (&r[2].x)[c]; t.w = (&r[3].x)[c];
        *reinterpret_cast<ushort4*>(sK + (dq * 4 + c) * 72 + tq * 4) = t;
      }
    }
    __syncthreads();

    bf16x8 av[2][2];
    #pragma unroll
    for (int i = 0; i < 2; ++i)
      #pragma unroll
      for (int ks = 0; ks < 2; ++ks)
        av[i][ks] = *reinterpret_cast<const bf16x8*>(
            sE + ((w * 2 + i) * 16 + col) * 72 + ks * 32 + quad * 8);
    #pragma unroll
    for (int j = 0; j < 4; ++j)
      #pragma unroll
      for (int ks = 0; ks < 2; ++ks) {
        const bf16x8 bv = *reinterpret_cast<const bf16x8*>(
            sK + (j * 16 + col) * 72 + ks * 32 + quad * 8);
        #pragma unroll
        for (int i = 0; i < 2; ++i)
          acc[i][j] = __builtin_amdgcn_mfma_f32_16x16x32_bf16(av[i][ks], bv, acc[i][j], 0, 0, 0);
      }
    __syncthreads();
  }

  float* op = part + ((size_t)bh * TCH + tc) * (KP * D_);
  #pragma unroll
  for (int i = 0; i < 2; ++i) {
    const int kkb = w * 32 + i * 16 + quad * 4;
    #pragma unroll
    for (int j = 0; j < 4; ++j) {
      const int d = j * 16 + col;
      #pragma unroll
      for (int rg = 0; rg < 4; ++rg)
        op[(kkb + rg) * D_ + d] = acc[i][j][rg];
    }
  }
}

// ---------------------------------------------------------------------------
// reduce_k: kprojh[bh][kk][d] (bf16) = sum_c part[bh][c][kk][d]
// ---------------------------------------------------------------------------
__global__ __launch_bounds__(256) void reduce_k(
    const float* __restrict__ part, unsigned short* __restrict__ kprojh)
{
  const int idx = blockIdx.x * 256 + threadIdx.x;   // over 128*8192
  const int bh = idx >> 13;
  const int i = idx & 8191;
  float s = 0.f;
  #pragma unroll
  for (int c = 0; c < TCH; ++c)
    s += part[((size_t)bh * TCH + c) * 8192 + i];
  kprojh[idx] = f2bf(s);
}

// ---------------------------------------------------------------------------
// reduce_v: vpT [bh][d][kk] bf16 = transpose(sum_c part[bh][c][kk][d])
// ---------------------------------------------------------------------------
__global__ __launch_bounds__(256) void reduce_v(
    const float* __restrict__ part, unsigned short* __restrict__ vpTh)
{
  __shared__ float sums[KP * 66];     // [kk][d] pitch 66
  const int bh = blockIdx.x;
  const int tid = threadIdx.x;
  #pragma unroll
  for (int j = 0; j < 32; ++j) {
    const int i = j * 256 + tid;      // kk = i>>6, d = i&63
    float s = 0.f;
    #pragma unroll
    for (int c = 0; c < TCH; ++c)
      s += part[((size_t)bh * TCH + c) * 8192 + i];
    sums[(i >> 6) * 66 + (i & 63)] = s;
  }
  __syncthreads();
  #pragma unroll
  for (int j = 0; j < 32; ++j) {
    const int i = j * 256 + tid;      // d = i>>7, kk = i&127
    vpTh[(size_t)bh * 8192 + i] = f2bf(sums[(i & 127) * 66 + (i >> 7)]);
  }
}

// ---------------------------------------------------------------------------
// MFMA attention (1-product): q bf16 from qkv[.., 0..C) (ld C3),
// kproj bf16 [kk][d], vpT bf16 [d][kk]; y bf16 out [M][C].
// ---------------------------------------------------------------------------
__global__ __launch_bounds__(256) void attn_mfma(
    const unsigned short* __restrict__ qkv, const unsigned short* __restrict__ kprojh,
    const unsigned short* __restrict__ vpTh, unsigned short* __restrict__ yh)
{
  // LDS union (35072 B): A: Qh@0(9216) Kp@9216(18432) end 27648
  //                      B: Vh@0(17408) Ps@17408(17408) atts@34816(256)
  __shared__ __attribute__((aligned(16))) char lds[35072];
  unsigned short* Qh = (unsigned short*)(lds);
  unsigned short* Kp = (unsigned short*)(lds + 9216);
  unsigned short* Vh = (unsigned short*)(lds);
  unsigned short* Ps = (unsigned short*)(lds + 17408);
  float* atts = (float*)(lds + 34816);

  const int tid  = threadIdx.x;
  const int lane = tid & 63;
  const int w    = tid >> 6;
  const int col  = lane & 15;
  const int quad = lane >> 4;
  const int bh = blockIdx.x >> 5;
  const int tch = blockIdx.x & 31;
  const int b = bh >> 4, h = bh & 15;
  const int t0 = tch * 64;

  { // stage Q (pitch 72) and Kp (pitch 72)
    const unsigned short* qg = qkv + (size_t)(b * T_ + t0) * C3 + h * D_;
    #pragma unroll
    for (int l = 0; l < 4; ++l) {
      const int idx = l * 256 + tid;
      const int t = idx >> 4, dc = (idx & 15) << 2;
      *reinterpret_cast<ushort4*>(Qh + t * 72 + dc) =
          *reinterpret_cast<const ushort4*>(qg + (size_t)t * C3 + dc);
    }
    const unsigned short* kg = kprojh + (size_t)bh * 8192;
    #pragma unroll
    for (int l = 0; l < 8; ++l) {
      const int idx = l * 256 + tid;
      const int kk = idx >> 4, dc = (idx & 15) << 2;
      *reinterpret_cast<ushort4*>(Kp + kk * 72 + dc) =
          *reinterpret_cast<const ushort4*>(kg + kk * 64 + dc);
    }
  }
  __syncthreads();

  // S^T = Kp(A) @ Q^T(B): m=kk (8 tiles), n=t (wave strip), k=d (2 steps)
  f32x4 s[8];
  #pragma unroll
  for (int i = 0; i < 8; ++i) s[i] = (f32x4){0.f, 0.f, 0.f, 0.f};
  bf16x8 bq[2];
  #pragma unroll
  for (int ks = 0; ks < 2; ++ks)
    bq[ks] = *reinterpret_cast<const bf16x8*>(
        Qh + (w * 16 + col) * 72 + ks * 32 + quad * 8);
  #pragma unroll
  for (int i = 0; i < 8; ++i)
    #pragma unroll
    for (int ks = 0; ks < 2; ++ks) {
      const bf16x8 a = *reinterpret_cast<const bf16x8*>(
          Kp + (i * 16 + col) * 72 + ks * 32 + quad * 8);
      s[i] = __builtin_amdgcn_mfma_f32_16x16x32_bf16(a, bq[ks], s[i], 0, 0, 0);
    }

  // softmax over kk (t = w*16+col)
  float mx = -3.0e38f;
  #pragma unroll
  for (int i = 0; i < 8; ++i)
    #pragma unroll
    for (int rg = 0; rg < 4; ++rg) {
      s[i][rg] *= 0.125f;
      mx = fmaxf(mx, s[i][rg]);
    }
  mx = fmaxf(mx, __shfl_xor(mx, 16));
  mx = fmaxf(mx, __shfl_xor(mx, 32));
  float sum = 0.f;
  #pragma unroll
  for (int i = 0; i < 8; ++i)
    #pragma unroll
    for (int rg = 0; rg < 4; ++rg) {
      const float e = __expf(s[i][rg] - mx);
      s[i][rg] = e;
      sum += e;
    }
  sum += __shfl_xor(sum, 16);
  sum += __shfl_xor(sum, 32);
  const float inv = 1.f / sum;
  __syncthreads();

  { // stage Vp (pitch 136)
    const unsigned short* vg = vpTh + (size_t)bh * 8192;
    #pragma unroll
    for (int l = 0; l < 8; ++l) {
      const int idx = l * 256 + tid;
      const int d = idx >> 5, kc = (idx & 31) << 2;
      *reinterpret_cast<ushort4*>(Vh + d * 136 + kc) =
          *reinterpret_cast<const ushort4*>(vg + d * 128 + kc);
    }
  }
  #pragma unroll
  for (int i = 0; i < 8; ++i) {
    ushort4 hp;
    hp.x = f2bf(s[i][0]); hp.y = f2bf(s[i][1]);
    hp.z = f2bf(s[i][2]); hp.w = f2bf(s[i][3]);
    *reinterpret_cast<ushort4*>(Ps + (w * 16 + col) * 136 + i * 16 + quad * 4) = hp;
  }
  if (quad == 0) atts[w * 16 + col] = inv;
  __syncthreads();

  // y = P(A) @ V(B): m=t (wave strip), n=d (4 tiles), k=kk (4 steps)
  f32x4 y[4];
  #pragma unroll
  for (int j = 0; j < 4; ++j) y[j] = (f32x4){0.f, 0.f, 0.f, 0.f};
  bf16x8 ap[4];
  #pragma unroll
  for (int ks = 0; ks < 4; ++ks)
    ap[ks] = *reinterpret_cast<const bf16x8*>(
        Ps + (w * 16 + col) * 136 + ks * 32 + quad * 8);
  #pragma unroll
  for (int j = 0; j < 4; ++j)
    #pragma unroll
    for (int ks = 0; ks < 4; ++ks) {
      const bf16x8 bv = *reinterpret_cast<const bf16x8*>(
          Vh + (j * 16 + col) * 136 + ks * 32 + quad * 8);
      y[j] = __builtin_amdgcn_mfma_f32_16x16x32_bf16(ap[ks], bv, y[j], 0, 0, 0);
    }

  const f32x4 inv4 = *reinterpret_cast<const f32x4*>(atts + w * 16 + quad * 4);
  #pragma unroll
  for (int j = 0; j < 4; ++j)
    #pragma unroll
    for (int rg = 0; rg < 4; ++rg) {
      const int t = t0 + w * 16 + quad * 4 + rg;
      const int d = j * 16 + col;
      yh[(size_t)(b * T_ + t) * C_ + h * D_ + d] = f2bf(y[j][rg] * inv4[rg]);
    }
}

// ---------------------------------------------------------------------------
extern "C" void kernel_launch(void* const* d_in, const int* in_sizes, int n_in,
                              void* d_out, int out_size, void* d_ws, size_t ws_size,
                              hipStream_t stream) {
  (void)in_sizes; (void)n_in; (void)out_size; (void)ws_size;
  const float* x      = (const float*)d_in[0];
  const float* W_attn = (const float*)d_in[1];
  const float* b_attn = (const float*)d_in[2];
  const float* W_proj = (const float*)d_in[3];
  const float* b_proj = (const float*)d_in[4];
  const float* E      = (const float*)d_in[5];
  const float* F      = (const float*)d_in[6];
  float* out = (float*)d_out;

  // ws regions, ~180.4 MB peak:
  unsigned short* xh   = (unsigned short*)d_ws;          // [M][C]  33.55 MB
  unsigned short* qkvh = xh + (size_t)M_ * C_;           // [M][3C] 100.66 MB
  unsigned short* WaT  = qkvh + (size_t)M_ * C3;         // [3072][1024] 6.29 MB
  unsigned short* WpT  = WaT + (size_t)C3 * C_;          // [1024][1024] 2.10 MB
  unsigned short* Eh   = WpT + (size_t)C_ * C_;          // 8.39 MB
  unsigned short* Fh   = Eh + (size_t)H_ * KP * T_;      // 8.39 MB
  float* part = (float*)(Fh + (size_t)H_ * KP * T_);     // 16.78 MB
  unsigned short* kprojh = (unsigned short*)(part + (size_t)B_ * H_ * TCH * KP * D_);
  unsigned short* vpTh   = kprojh + (size_t)B_ * H_ * KP * D_;   // 2.10 MB each
  unsigned short* yh = xh;                               // x dead after qkv GEMM

  // 0) casts / transposes
  cast_bf16<<<(M_ * C_ / 4 + 255) / 256, 256, 0, stream>>>(x, xh, M_ * C_ / 4);
  cast_bf16<<<(H_ * KP * T_ / 4 + 255) / 256, 256, 0, stream>>>(E, Eh, H_ * KP * T_ / 4);
  cast_bf16<<<(H_ * KP * T_ / 4 + 255) / 256, 256, 0, stream>>>(F, Fh, H_ * KP * T_ / 4);
  cast_tr<<<dim3(C3 / 32, C_ / 32), 256, 0, stream>>>(W_attn, WaT, C_, C3);
  cast_tr<<<dim3(C_ / 32, C_ / 32), 256, 0, stream>>>(W_proj, WpT, C_, C_);

  // 1) qkv = x @ W_attn + b_attn  (fused, N=3072, bf16 out) — 8-phase 256²
  gemm256<true><<<dim3((M_ / 256) * (C3 / 256)), 512, 0, stream>>>(
      xh, WaT, b_attn, nullptr, qkvh, C3);

  // 2) kproj = E @ k  (k = qkv cols [C,2C))
  proj_mfma<<<dim3(B_ * H_, TCH), 256, 0, stream>>>(Eh, qkvh + C_, C3, part);
  reduce_k<<<(B_ * H_ * KP * D_) / 256, 256, 0, stream>>>(part, kprojh);

  // 3) vpT = transpose(F @ v)  (v = qkv cols [2C,3C))
  proj_mfma<<<dim3(B_ * H_, TCH), 256, 0, stream>>>(Fh, qkvh + 2 * C_, C3, part);
  reduce_v<<<B_ * H_, 256, 0, stream>>>(part, vpTh);

  // 4) MFMA attention -> y bf16 (overwrites x region)
  attn_mfma<<<B_ * H_ * (T_ / 64), 256, 0, stream>>>(qkvh, kprojh, vpTh, yh);

  // 5) out = y @ W_proj + b_proj (fp32 out) — 8-phase 256²
  gemm256<false><<<dim3((M_ / 256) * (C_ / 256)), 512, 0, stream>>>(
      yh, WpT, b_proj, out, nullptr, C_);
}

// Round 4
// 380.161 us; speedup vs baseline: 1.0946x; 1.0114x over previous
//
#include <hip/hip_runtime.h>
#include <math.h>

// LinformerAttention on MI355X — Round 10: R9 (fragment-linear LDS, zero bank
// conflicts) minus the scheduler pinning: all sched_barrier(0) and manual
// per-phase lgkmcnt(0) removed (m141 lesson — compiler emits fine-grained
// lgkmcnt itself; the walls blocked ds_read/VALU hiding under MFMA).
// Schedule (phases, counted vmcnt(6), setprio, XCD swizzle) otherwise
// identical. B=8 T=2048 C=1024 H=16 D=64 Kproj=128. ws ~180 MB.

constexpr int B_ = 8, T_ = 2048, C_ = 1024, H_ = 16, D_ = 64, KP = 128;
constexpr int M_ = B_ * T_;            // 16384
constexpr int C3 = 3 * C_;             // 3072
constexpr int K_ = C_;                 // GEMM K = 1024
constexpr int NT = K_ / 64;            // 16 K-tiles of 64
constexpr int TCH = 4;                 // proj t-chunks of 512

typedef __attribute__((ext_vector_type(8))) short bf16x8;   // 8 bf16 = 4 VGPR
typedef __attribute__((ext_vector_type(4))) float f32x4;

__device__ __forceinline__ unsigned short f2bf(float f) {
  unsigned u = __builtin_bit_cast(unsigned, f);
  u += 0x7FFFu + ((u >> 16) & 1u);     // round-to-nearest-even
  return (unsigned short)(u >> 16);
}
__device__ __forceinline__ float bf2f(unsigned short h) {
  unsigned u = ((unsigned)h) << 16;
  return __builtin_bit_cast(float, u);
}

#define GLOAD_LDS16(gptr, lptr)                                                \
  __builtin_amdgcn_global_load_lds(                                            \
      (const __attribute__((address_space(1))) void*)(gptr),                   \
      (__attribute__((address_space(3))) void*)(lptr), 16, 0, 0)

// ---------------------------------------------------------------------------
// fp32 -> bf16 (hi) cast, row-major. n4 = n/4.
// ---------------------------------------------------------------------------
__global__ __launch_bounds__(256) void cast_bf16(
    const float* __restrict__ in, unsigned short* __restrict__ hi, int n4)
{
  int i = blockIdx.x * 256 + threadIdx.x;
  if (i >= n4) return;
  const float4 v = reinterpret_cast<const float4*>(in)[i];
  ushort4 h;
  h.x = f2bf(v.x); h.y = f2bf(v.y); h.z = f2bf(v.z); h.w = f2bf(v.w);
  reinterpret_cast<ushort4*>(hi)[i] = h;
}

// ---------------------------------------------------------------------------
// Transpose + bf16: W [rows][cols] fp32 -> T [cols][rows] bf16.
// ---------------------------------------------------------------------------
__global__ __launch_bounds__(256) void cast_tr(
    const float* __restrict__ W, unsigned short* __restrict__ Tb,
    int rows, int cols)
{
  __shared__ float tile[32][33];
  const int c0 = blockIdx.x * 32, r0 = blockIdx.y * 32;
  const int tx = threadIdx.x & 31, ty = threadIdx.x >> 5;   // ty 0..7
  #pragma unroll
  for (int i = 0; i < 4; ++i)
    tile[ty + i * 8][tx] = W[(size_t)(r0 + ty + i * 8) * cols + c0 + tx];
  __syncthreads();
  #pragma unroll
  for (int i = 0; i < 4; ++i) {
    const int cr = ty + i * 8;
    Tb[(size_t)(c0 + cr) * rows + r0 + tx] = f2bf(tile[tx][cr]);
  }
}

// ---------------------------------------------------------------------------
// 256x256 8-phase GEMM: C(16384 x ldc) = A(MxK) @ BT^T + bias, K=1024.
// BT is [N][K] bf16. 512 threads = 8 waves (2M x 4N); per-wave 128x64 out.
// LDS 128 KiB static: 2 buf x (A 32KB + B 32KB), each 2 halves of 16KB.
//
// FRAGMENT-LINEAR layout. A half H (16KB) = 16 subtiles of 1024B:
//   byte = H*16384 + rg*2048 + ks*1024 + (q*16 + c)*16
//   logical: lds-row rl = rg*16+c (rg 0..7), k-elem = ks*32 + q*8 + e
//   global m row = (rl>>6)*128 + (rl&63) + H*64
// B half H likewise with n row = (rl>>5)*64 + (rl&31) + H*32.
// MFMA fragment reads are base + lane*16: ZERO bank conflicts (verified R9:
// SQ_LDS_BANK_CONFLICT == 0).
// Staging: dest = region + w*2048 + l*1024 + lane*16 (linear, rg=w, ks=l);
// source per lane (q=lane>>4, c=lane&15): row w*16+c, k = kt*64 + l*32 + q*8.
// Schedule: 4 phases/K-tile, 1 half staged per phase, boundary vmcnt(6);
// NO sched_barrier / manual lgkmcnt(0) — compiler schedules the interior.
// ---------------------------------------------------------------------------
template <bool BFOUT>
__global__ __launch_bounds__(512, 2) void gemm256(
    const unsigned short* __restrict__ A, const unsigned short* __restrict__ BT,
    const float* __restrict__ bias, float* __restrict__ Cf,
    unsigned short* __restrict__ Cb, int ldc)
{
  __shared__ __attribute__((aligned(16))) char lds[131072];

  const int tid  = threadIdx.x;
  const int lane = tid & 63;
  const int w    = tid >> 6;           // 0..7
  const int wr   = w >> 2;             // 0..1 (M)
  const int wc   = w & 3;              // 0..3 (N)
  const int col  = lane & 15;
  const int quad = lane >> 4;

  // T1: bijective XCD-chunked block swizzle (gridDim.x % 8 == 0 here).
  const int ntx = ldc >> 8;
  int wg = blockIdx.x;
  wg = (wg & 7) * (gridDim.x >> 3) + (wg >> 3);
  const int bx = wg % ntx, by = wg / ntx;
  const int m0 = by << 8, n0 = bx << 8;

  // --- staging geometry (per thread, 2 loads per half) ---
  const int kq   = quad * 8;                 // k sub-offset (bf16 elems)
  const int rowL = w * 16 + col;             // logical lds-row 0..127 (rg = w)
  const int mOff = (rowL >> 6) * 128 + (rowL & 63);
  const int nOff = (rowL >> 5) * 64 + (rowL & 31);
  const int dstO = w * 2048 + lane * 16;     // + l*1024

#define STAGE_A(H, KT0, BUFSEL)                                                \
  { const int kb_ = (KT0) * 64 + kq;                                           \
    _Pragma("unroll")                                                          \
    for (int l = 0; l < 2; ++l)                                                \
      GLOAD_LDS16(A + (size_t)(m0 + mOff + (H) * 64) * K_ + kb_ + l * 32,      \
                  lds + (BUFSEL) * 65536 + (H) * 16384 + dstO + l * 1024); }

#define STAGE_B(H, KT0, BUFSEL)                                                \
  { const int kb_ = (KT0) * 64 + kq;                                           \
    _Pragma("unroll")                                                          \
    for (int l = 0; l < 2; ++l)                                                \
      GLOAD_LDS16(BT + (size_t)(n0 + nOff + (H) * 32) * K_ + kb_ + l * 32,     \
                  lds + (BUFSEL) * 65536 + 32768 + (H) * 16384 + dstO +        \
                      l * 1024); }

  // --- ds_read fragment addressing: base + lane*16, fully linear ---
  const int laneB = lane * 16;
  const int aB0 = wr * 8192 + laneB;           // A half 0, rg = wr*4 + i
  const int aB1 = 16384 + aB0;                 // A half 1
  const int bB0 = 32768 + wc * 4096 + laneB;   // B half 0, rg = wc*2 + j
  const int bB1 = 16384 + bB0;                 // B half 1

  f32x4 acc[8][4];
  #pragma unroll
  for (int a = 0; a < 8; ++a)
    #pragma unroll
    for (int c = 0; c < 4; ++c)
      acc[a][c] = (f32x4){0.f, 0.f, 0.f, 0.f};

  bf16x8 av[4][2], b0v[2][2], b1v[2][2];

#define MFMA_Q(QM, QN, BV)                                                     \
  __builtin_amdgcn_s_setprio(1);                                               \
  _Pragma("unroll")                                                            \
  for (int j = 0; j < 2; ++j)                                                  \
    _Pragma("unroll")                                                          \
    for (int ks = 0; ks < 2; ++ks)                                             \
      _Pragma("unroll")                                                        \
      for (int i = 0; i < 4; ++i)                                              \
        acc[(QM) * 4 + i][(QN) * 2 + j] =                                      \
            __builtin_amdgcn_mfma_f32_16x16x32_bf16(                           \
                av[i][ks], BV[j][ks], acc[(QM) * 4 + i][(QN) * 2 + j], 0, 0, 0);\
  __builtin_amdgcn_s_setprio(0);

  // --- prologue: tile0 fully + tile1 {A0,B0,B1}; vmcnt(4) then vmcnt(6) ---
  STAGE_A(0, 0, 0);
  STAGE_B(0, 0, 0);
  STAGE_B(1, 0, 0);
  STAGE_A(1, 0, 0);
  asm volatile("s_waitcnt vmcnt(4)" ::: "memory");
  STAGE_A(0, 1, 1);
  STAGE_B(0, 1, 1);
  STAGE_B(1, 1, 1);
  asm volatile("s_waitcnt vmcnt(6)" ::: "memory");
  __builtin_amdgcn_s_barrier();

#define TILE(KT, CUR)                                                          \
  {                                                                            \
    const char* cb = lds + (CUR) * 65536;                                      \
    /* phase 1: quadrant (0,0); 12 ds_read; stage A1(t+1) */                   \
    _Pragma("unroll")                                                          \
    for (int i = 0; i < 4; ++i)                                                \
      _Pragma("unroll")                                                        \
      for (int ks = 0; ks < 2; ++ks)                                           \
        av[i][ks] = *reinterpret_cast<const bf16x8*>(                          \
            cb + aB0 + i * 2048 + ks * 1024);                                  \
    _Pragma("unroll")                                                          \
    for (int j = 0; j < 2; ++j)                                                \
      _Pragma("unroll")                                                        \
      for (int ks = 0; ks < 2; ++ks)                                           \
        b0v[j][ks] = *reinterpret_cast<const bf16x8*>(                         \
            cb + bB0 + j * 2048 + ks * 1024);                                  \
    if ((KT) + 1 < NT) { STAGE_A(1, (KT) + 1, (CUR) ^ 1); }                    \
    asm volatile("s_waitcnt lgkmcnt(8)" ::: "memory");                         \
    __builtin_amdgcn_s_barrier();                                              \
    MFMA_Q(0, 0, b0v);                                                         \
    __builtin_amdgcn_s_barrier();                                              \
    /* phase 2: quadrant (0,1); 4 ds_read; stage A0(t+2) */                    \
    _Pragma("unroll")                                                          \
    for (int j = 0; j < 2; ++j)                                                \
      _Pragma("unroll")                                                        \
      for (int ks = 0; ks < 2; ++ks)                                           \
        b1v[j][ks] = *reinterpret_cast<const bf16x8*>(                         \
            cb + bB1 + j * 2048 + ks * 1024);                                  \
    if ((KT) + 2 < NT) { STAGE_A(0, (KT) + 2, (CUR)); }                        \
    __builtin_amdgcn_s_barrier();                                              \
    MFMA_Q(0, 1, b1v);                                                         \
    __builtin_amdgcn_s_barrier();                                              \
    /* phase 3: quadrant (1,1); 8 ds_read; stage B0(t+2) */                    \
    _Pragma("unroll")                                                          \
    for (int i = 0; i < 4; ++i)                                                \
      _Pragma("unroll")                                                        \
      for (int ks = 0; ks < 2; ++ks)                                           \
        av[i][ks] = *reinterpret_cast<const bf16x8*>(                          \
            cb + aB1 + i * 2048 + ks * 1024);                                  \
    if ((KT) + 2 < NT) { STAGE_B(0, (KT) + 2, (CUR)); }                        \
    __builtin_amdgcn_s_barrier();                                              \
    MFMA_Q(1, 1, b1v);                                                         \
    __builtin_amdgcn_s_barrier();                                              \
    /* phase 4: quadrant (1,0); 0 ds_read; stage B1(t+2); boundary vmcnt */    \
    if ((KT) + 2 < NT) { STAGE_B(1, (KT) + 2, (CUR)); }                        \
    __builtin_amdgcn_s_barrier();                                              \
    MFMA_Q(1, 0, b0v);                                                         \
    if ((KT) < NT - 2) {                                                       \
      asm volatile("s_waitcnt vmcnt(6)" ::: "memory");                         \
    } else if ((KT) == NT - 2) {                                               \
      asm volatile("s_waitcnt vmcnt(0)" ::: "memory");                         \
    }                                                                          \
    __builtin_amdgcn_s_barrier();                                              \
  }

  for (int kt = 0; kt < NT; kt += 2) {
    TILE(kt, 0);
    TILE(kt + 1, 1);
  }
#undef TILE
#undef MFMA_Q
#undef STAGE_A
#undef STAGE_B

  // --- epilogue: C/D layout col=lane&15, row=quad*4+reg (session-verified) --
  #pragma unroll
  for (int a = 0; a < 8; ++a) {
    const int r = m0 + wr * 128 + (a >> 2) * 64 + (a & 3) * 16 + quad * 4;
    #pragma unroll
    for (int c = 0; c < 4; ++c) {
      const int cc = n0 + wc * 64 + (c >> 1) * 32 + (c & 1) * 16 + col;
      const float bv = bias[cc];
      #pragma unroll
      for (int rg = 0; rg < 4; ++rg) {
        const float v = acc[a][c][rg] + bv;
        const size_t o = (size_t)(r + rg) * ldc + cc;
        if constexpr (BFOUT) Cb[o] = f2bf(v);
        else Cf[o] = v;
      }
    }
  }
}

// ---------------------------------------------------------------------------
// MFMA proj (1-product): part[(bh*TCH+tc)][kk=128][d=64] fp32 =
//   sum_{t in 512-chunk} E[h][kk][t] * k[b*T+t][h*64+d]
// ---------------------------------------------------------------------------
__global__ __launch_bounds__(256) void proj_mfma(
    const unsigned short* __restrict__ Eh, const unsigned short* __restrict__ kb,
    int ldk, float* __restrict__ part)
{
  __shared__ unsigned short sE[KP * 72];           // 18.0 KB
  __shared__ unsigned short sK[D_ * 72];           //  9.0 KB

  const int bh = blockIdx.x;
  const int tc = blockIdx.y;
  const int b = bh >> 4, h = bh & 15;
  const int tid = threadIdx.x;
  const int lane = tid & 63;
  const int w = tid >> 6;
  const int col = lane & 15;
  const int quad = lane >> 4;
  const int tq = tid >> 4;            // 0..15 -> t-base tq*4
  const int dq = tid & 15;            // 0..15 -> d-base dq*4

  f32x4 acc[2][4];
  #pragma unroll
  for (int i = 0; i < 2; ++i)
    #pragma unroll
    for (int j = 0; j < 4; ++j) acc[i][j] = (f32x4){0.f, 0.f, 0.f, 0.f};

  for (int s = 0; s < 8; ++s) {
    const int t0 = tc * 512 + s * 64;
    #pragma unroll
    for (int l = 0; l < 4; ++l) {
      const int idx = l * 256 + tid;
      const int kk = idx >> 3, seg = idx & 7;
      *reinterpret_cast<uint4*>(sE + kk * 72 + seg * 8) =
          *reinterpret_cast<const uint4*>(
              Eh + (size_t)(h * KP + kk) * T_ + t0 + seg * 8);
    }
    {
      const size_t gbase = (size_t)(b * T_ + t0 + tq * 4) * ldk + h * D_ + dq * 4;
      ushort4 r[4];
      #pragma unroll
      for (int rr = 0; rr < 4; ++rr)
        r[rr] = *reinterpret_cast<const ushort4*>(kb + gbase + (size_t)rr * ldk);
      #pragma unroll
      for (int c = 0; c < 4; ++c) {
        ushort4 t;
        t.x = (&r[0].x)[c]; t.y = (&r[1].x)[c];
        t.z = (&r[2].x)[c]; t.w = (&r[3].x)[c];
        *reinterpret_cast<ushort4*>(sK + (dq * 4 + c) * 72 + tq * 4) = t;
      }
    }
    __syncthreads();

    bf16x8 av[2][2];
    #pragma unroll
    for (int i = 0; i < 2; ++i)
      #pragma unroll
      for (int ks = 0; ks < 2; ++ks)
        av[i][ks] = *reinterpret_cast<const bf16x8*>(
            sE + ((w * 2 + i) * 16 + col) * 72 + ks * 32 + quad * 8);
    #pragma unroll
    for (int j = 0; j < 4; ++j)
      #pragma unroll
      for (int ks = 0; ks < 2; ++ks) {
        const bf16x8 bv = *reinterpret_cast<const bf16x8*>(
            sK + (j * 16 + col) * 72 + ks * 32 + quad * 8);
        #pragma unroll
        for (int i = 0; i < 2; ++i)
          acc[i][j] = __builtin_amdgcn_mfma_f32_16x16x32_bf16(av[i][ks], bv, acc[i][j], 0, 0, 0);
      }
    __syncthreads();
  }

  float* op = part + ((size_t)bh * TCH + tc) * (KP * D_);
  #pragma unroll
  for (int i = 0; i < 2; ++i) {
    const int kkb = w * 32 + i * 16 + quad * 4;
    #pragma unroll
    for (int j = 0; j < 4; ++j) {
      const int d = j * 16 + col;
      #pragma unroll
      for (int rg = 0; rg < 4; ++rg)
        op[(kkb + rg) * D_ + d] = acc[i][j][rg];
    }
  }
}

// ---------------------------------------------------------------------------
// reduce_k: kprojh[bh][kk][d] (bf16) = sum_c part[bh][c][kk][d]
// ---------------------------------------------------------------------------
__global__ __launch_bounds__(256) void reduce_k(
    const float* __restrict__ part, unsigned short* __restrict__ kprojh)
{
  const int idx = blockIdx.x * 256 + threadIdx.x;   // over 128*8192
  const int bh = idx >> 13;
  const int i = idx & 8191;
  float s = 0.f;
  #pragma unroll
  for (int c = 0; c < TCH; ++c)
    s += part[((size_t)bh * TCH + c) * 8192 + i];
  kprojh[idx] = f2bf(s);
}

// ---------------------------------------------------------------------------
// reduce_v: vpT [bh][d][kk] bf16 = transpose(sum_c part[bh][c][kk][d])
// ---------------------------------------------------------------------------
__global__ __launch_bounds__(256) void reduce_v(
    const float* __restrict__ part, unsigned short* __restrict__ vpTh)
{
  __shared__ float sums[KP * 66];     // [kk][d] pitch 66
  const int bh = blockIdx.x;
  const int tid = threadIdx.x;
  #pragma unroll
  for (int j = 0; j < 32; ++j) {
    const int i = j * 256 + tid;      // kk = i>>6, d = i&63
    float s = 0.f;
    #pragma unroll
    for (int c = 0; c < TCH; ++c)
      s += part[((size_t)bh * TCH + c) * 8192 + i];
    sums[(i >> 6) * 66 + (i & 63)] = s;
  }
  __syncthreads();
  #pragma unroll
  for (int j = 0; j < 32; ++j) {
    const int i = j * 256 + tid;      // d = i>>7, kk = i&127
    vpTh[(size_t)bh * 8192 + i] = f2bf(sums[(i & 127) * 66 + (i >> 7)]);
  }
}

// ---------------------------------------------------------------------------
// MFMA attention (1-product): q bf16 from qkv[.., 0..C) (ld C3),
// kproj bf16 [kk][d], vpT bf16 [d][kk]; y bf16 out [M][C].
// ---------------------------------------------------------------------------
__global__ __launch_bounds__(256) void attn_mfma(
    const unsigned short* __restrict__ qkv, const unsigned short* __restrict__ kprojh,
    const unsigned short* __restrict__ vpTh, unsigned short* __restrict__ yh)
{
  // LDS union (35072 B): A: Qh@0(9216) Kp@9216(18432) end 27648
  //                      B: Vh@0(17408) Ps@17408(17408) atts@34816(256)
  __shared__ __attribute__((aligned(16))) char lds[35072];
  unsigned short* Qh = (unsigned short*)(lds);
  unsigned short* Kp = (unsigned short*)(lds + 9216);
  unsigned short* Vh = (unsigned short*)(lds);
  unsigned short* Ps = (unsigned short*)(lds + 17408);
  float* atts = (float*)(lds + 34816);

  const int tid  = threadIdx.x;
  const int lane = tid & 63;
  const int w    = tid >> 6;
  const int col  = lane & 15;
  const int quad = lane >> 4;
  const int bh = blockIdx.x >> 5;
  const int tch = blockIdx.x & 31;
  const int b = bh >> 4, h = bh & 15;
  const int t0 = tch * 64;

  { // stage Q (pitch 72) and Kp (pitch 72)
    const unsigned short* qg = qkv + (size_t)(b * T_ + t0) * C3 + h * D_;
    #pragma unroll
    for (int l = 0; l < 4; ++l) {
      const int idx = l * 256 + tid;
      const int t = idx >> 4, dc = (idx & 15) << 2;
      *reinterpret_cast<ushort4*>(Qh + t * 72 + dc) =
          *reinterpret_cast<const ushort4*>(qg + (size_t)t * C3 + dc);
    }
    const unsigned short* kg = kprojh + (size_t)bh * 8192;
    #pragma unroll
    for (int l = 0; l < 8; ++l) {
      const int idx = l * 256 + tid;
      const int kk = idx >> 4, dc = (idx & 15) << 2;
      *reinterpret_cast<ushort4*>(Kp + kk * 72 + dc) =
          *reinterpret_cast<const ushort4*>(kg + kk * 64 + dc);
    }
  }
  __syncthreads();

  // S^T = Kp(A) @ Q^T(B): m=kk (8 tiles), n=t (wave strip), k=d (2 steps)
  f32x4 s[8];
  #pragma unroll
  for (int i = 0; i < 8; ++i) s[i] = (f32x4){0.f, 0.f, 0.f, 0.f};
  bf16x8 bq[2];
  #pragma unroll
  for (int ks = 0; ks < 2; ++ks)
    bq[ks] = *reinterpret_cast<const bf16x8*>(
        Qh + (w * 16 + col) * 72 + ks * 32 + quad * 8);
  #pragma unroll
  for (int i = 0; i < 8; ++i)
    #pragma unroll
    for (int ks = 0; ks < 2; ++ks) {
      const bf16x8 a = *reinterpret_cast<const bf16x8*>(
          Kp + (i * 16 + col) * 72 + ks * 32 + quad * 8);
      s[i] = __builtin_amdgcn_mfma_f32_16x16x32_bf16(a, bq[ks], s[i], 0, 0, 0);
    }

  // softmax over kk (t = w*16+col)
  float mx = -3.0e38f;
  #pragma unroll
  for (int i = 0; i < 8; ++i)
    #pragma unroll
    for (int rg = 0; rg < 4; ++rg) {
      s[i][rg] *= 0.125f;
      mx = fmaxf(mx, s[i][rg]);
    }
  mx = fmaxf(mx, __shfl_xor(mx, 16));
  mx = fmaxf(mx, __shfl_xor(mx, 32));
  float sum = 0.f;
  #pragma unroll
  for (int i = 0; i < 8; ++i)
    #pragma unroll
    for (int rg = 0; rg < 4; ++rg) {
      const float e = __expf(s[i][rg] - mx);
      s[i][rg] = e;
      sum += e;
    }
  sum += __shfl_xor(sum, 16);
  sum += __shfl_xor(sum, 32);
  const float inv = 1.f / sum;
  __syncthreads();

  { // stage Vp (pitch 136)
    const unsigned short* vg = vpTh + (size_t)bh * 8192;
    #pragma unroll
    for (int l = 0; l < 8; ++l) {
      const int idx = l * 256 + tid;
      const int d = idx >> 5, kc = (idx & 31) << 2;
      *reinterpret_cast<ushort4*>(Vh + d * 136 + kc) =
          *reinterpret_cast<const ushort4*>(vg + d * 128 + kc);
    }
  }
  #pragma unroll
  for (int i = 0; i < 8; ++i) {
    ushort4 hp;
    hp.x = f2bf(s[i][0]); hp.y = f2bf(s[i][1]);
    hp.z = f2bf(s[i][2]); hp.w = f2bf(s[i][3]);
    *reinterpret_cast<ushort4*>(Ps + (w * 16 + col) * 136 + i * 16 + quad * 4) = hp;
  }
  if (quad == 0) atts[w * 16 + col] = inv;
  __syncthreads();

  // y = P(A) @ V(B): m=t (wave strip), n=d (4 tiles), k=kk (4 steps)
  f32x4 y[4];
  #pragma unroll
  for (int j = 0; j < 4; ++j) y[j] = (f32x4){0.f, 0.f, 0.f, 0.f};
  bf16x8 ap[4];
  #pragma unroll
  for (int ks = 0; ks < 4; ++ks)
    ap[ks] = *reinterpret_cast<const bf16x8*>(
        Ps + (w * 16 + col) * 136 + ks * 32 + quad * 8);
  #pragma unroll
  for (int j = 0; j < 4; ++j)
    #pragma unroll
    for (int ks = 0; ks < 4; ++ks) {
      const bf16x8 bv = *reinterpret_cast<const bf16x8*>(
          Vh + (j * 16 + col) * 136 + ks * 32 + quad * 8);
      y[j] = __builtin_amdgcn_mfma_f32_16x16x32_bf16(ap[ks], bv, y[j], 0, 0, 0);
    }

  const f32x4 inv4 = *reinterpret_cast<const f32x4*>(atts + w * 16 + quad * 4);
  #pragma unroll
  for (int j = 0; j < 4; ++j)
    #pragma unroll
    for (int rg = 0; rg < 4; ++rg) {
      const int t = t0 + w * 16 + quad * 4 + rg;
      const int d = j * 16 + col;
      yh[(size_t)(b * T_ + t) * C_ + h * D_ + d] = f2bf(y[j][rg] * inv4[rg]);
    }
}

// ---------------------------------------------------------------------------
extern "C" void kernel_launch(void* const* d_in, const int* in_sizes, int n_in,
                              void* d_out, int out_size, void* d_ws, size_t ws_size,
                              hipStream_t stream) {
  (void)in_sizes; (void)n_in; (void)out_size; (void)ws_size;
  const float* x      = (const float*)d_in[0];
  const float* W_attn = (const float*)d_in[1];
  const float* b_attn = (const float*)d_in[2];
  const float* W_proj = (const float*)d_in[3];
  const float* b_proj = (const float*)d_in[4];
  const float* E      = (const float*)d_in[5];
  const float* F      = (const float*)d_in[6];
  float* out = (float*)d_out;

  // ws regions, ~180.4 MB peak:
  unsigned short* xh   = (unsigned short*)d_ws;          // [M][C]  33.55 MB
  unsigned short* qkvh = xh + (size_t)M_ * C_;           // [M][3C] 100.66 MB
  unsigned short* WaT  = qkvh + (size_t)M_ * C3;         // [3072][1024] 6.29 MB
  unsigned short* WpT  = WaT + (size_t)C3 * C_;          // [1024][1024] 2.10 MB
  unsigned short* Eh   = WpT + (size_t)C_ * C_;          // 8.39 MB
  unsigned short* Fh   = Eh + (size_t)H_ * KP * T_;      // 8.39 MB
  float* part = (float*)(Fh + (size_t)H_ * KP * T_);     // 16.78 MB
  unsigned short* kprojh = (unsigned short*)(part + (size_t)B_ * H_ * TCH * KP * D_);
  unsigned short* vpTh   = kprojh + (size_t)B_ * H_ * KP * D_;   // 2.10 MB each
  unsigned short* yh = xh;                               // x dead after qkv GEMM

  // 0) casts / transposes
  cast_bf16<<<(M_ * C_ / 4 + 255) / 256, 256, 0, stream>>>(x, xh, M_ * C_ / 4);
  cast_bf16<<<(H_ * KP * T_ / 4 + 255) / 256, 256, 0, stream>>>(E, Eh, H_ * KP * T_ / 4);
  cast_bf16<<<(H_ * KP * T_ / 4 + 255) / 256, 256, 0, stream>>>(F, Fh, H_ * KP * T_ / 4);
  cast_tr<<<dim3(C3 / 32, C_ / 32), 256, 0, stream>>>(W_attn, WaT, C_, C3);
  cast_tr<<<dim3(C_ / 32, C_ / 32), 256, 0, stream>>>(W_proj, WpT, C_, C_);

  // 1) qkv = x @ W_attn + b_attn  (fused, N=3072, bf16 out) — 8-phase 256²
  gemm256<true><<<dim3((M_ / 256) * (C3 / 256)), 512, 0, stream>>>(
      xh, WaT, b_attn, nullptr, qkvh, C3);

  // 2) kproj = E @ k  (k = qkv cols [C,2C))
  proj_mfma<<<dim3(B_ * H_, TCH), 256, 0, stream>>>(Eh, qkvh + C_, C3, part);
  reduce_k<<<(B_ * H_ * KP * D_) / 256, 256, 0, stream>>>(part, kprojh);

  // 3) vpT = transpose(F @ v)  (v = qkv cols [2C,3C))
  proj_mfma<<<dim3(B_ * H_, TCH), 256, 0, stream>>>(Fh, qkvh + 2 * C_, C3, part);
  reduce_v<<<B_ * H_, 256, 0, stream>>>(part, vpTh);

  // 4) MFMA attention -> y bf16 (overwrites x region)
  attn_mfma<<<B_ * H_ * (T_ / 64), 256, 0, stream>>>(qkvh, kprojh, vpTh, yh);

  // 5) out = y @ W_proj + b_proj (fp32 out) — 8-phase 256²
  gemm256<false><<<dim3((M_ / 256) * (C_ / 256)), 512, 0, stream>>>(
      yh, WpT, b_proj, out, nullptr, C_);
}